// Round 1
// baseline (798.253 us; speedup 1.0000x reference)
//
#include <hip/hip_runtime.h>
#include <cstdint>
#include <cstddef>

// ---------------- problem constants ----------------
#define BATCH 16
#define NBOX 25200
#define NCH 85          // 4 box + 1 obj + 80 cls
#define KPRE 1024
#define MAXDET 1000
#define NCAND_MAX 4096
#define HIST_SIZE 16384 // histogram over (key >> 18)

__device__ __forceinline__ unsigned key_of(float s) {
    // monotone map: larger score -> SMALLER key (ascending sort = descending score)
    unsigned u = __float_as_uint(s);
    unsigned m = (u & 0x80000000u) ? ~u : (u | 0x80000000u);
    return ~m;
}

// ---------------- kernel 1: per-box score/argmax, key + histogram ----------------
// one wave (64 lanes) per box; lanes cover the 80 class channels
__global__ __launch_bounds__(256) void score_kernel(const float* __restrict__ x,
                                                    unsigned* __restrict__ k32,
                                                    unsigned char* __restrict__ cls8,
                                                    unsigned* __restrict__ hist) {
    int gid = blockIdx.x * 256 + threadIdx.x;
    int wid = gid >> 6;                      // box id within [0, BATCH*NBOX)
    if (wid >= BATCH * NBOX) return;
    int lane = threadIdx.x & 63;
    size_t base = (size_t)wid * NCH;

    float obj = x[base + 4];
    float v1 = x[base + 5 + lane] * obj;     // classes 0..63
    int   c1 = lane;
    float v2 = -1.0f;
    int   c2 = 64 + lane;                    // classes 64..79
    if (lane < 16) v2 = x[base + 69 + lane] * obj;

    float v; int c;
    if (v2 > v1) { v = v2; c = c2; } else { v = v1; c = c1; }  // c1 < c2: tie -> lower idx

    // butterfly max+argmax, tie -> smaller class index (jnp.argmax = first occurrence)
    for (int off = 32; off; off >>= 1) {
        float ov = __shfl_xor(v, off);
        int   oc = __shfl_xor(c, off);
        if (ov > v || (ov == v && oc < c)) { v = ov; c = oc; }
    }

    if (lane == 0) {
        bool valid = (obj > 0.25f) && (v > 0.25f);
        float score = valid ? v : -1.0f;
        unsigned k = key_of(score);
        k32[wid] = k;
        cls8[wid] = (unsigned char)c;
        int b = wid / NBOX;
        atomicAdd(&hist[b * HIST_SIZE + (k >> 18)], 1u);
    }
}

// ---------------- kernel 2: find histogram cutoff prefix covering rank KPRE ----------------
__global__ __launch_bounds__(256) void select_cutoff(const unsigned* __restrict__ hist,
                                                     unsigned* __restrict__ cutoff) {
    int b = blockIdx.x, t = threadIdx.x;
    __shared__ unsigned part[256];
    const unsigned* h = hist + (size_t)b * HIST_SIZE;
    unsigned s = 0;
    for (int j = 0; j < HIST_SIZE / 256; j++) s += h[t * (HIST_SIZE / 256) + j];
    part[t] = s;
    __syncthreads();
    if (t == 0) {
        unsigned cum = 0;
        int chunk = 0;
        for (; chunk < 256; chunk++) {
            if (cum + part[chunk] >= KPRE) break;
            cum += part[chunk];
        }
        unsigned P = HIST_SIZE - 1;
        if (chunk < 256) {
            int base = chunk * (HIST_SIZE / 256);
            for (int j = 0; j < HIST_SIZE / 256; j++) {
                cum += h[base + j];
                if (cum >= KPRE) { P = base + j; break; }
            }
        }
        cutoff[b] = P;
    }
}

// ---------------- kernel 3: compact candidates (key64 = k32<<32 | idx) ----------------
__global__ __launch_bounds__(256) void compact_kernel(const unsigned* __restrict__ k32,
                                                      const unsigned* __restrict__ cutoff,
                                                      unsigned* __restrict__ ncand,
                                                      unsigned long long* __restrict__ cand) {
    int gi = blockIdx.x * 256 + threadIdx.x;
    if (gi >= BATCH * NBOX) return;
    int b = gi / NBOX;
    unsigned k = k32[gi];
    if ((k >> 18) <= cutoff[b]) {
        unsigned pos = atomicAdd(&ncand[b], 1u);
        if (pos < NCAND_MAX)
            cand[(size_t)b * NCAND_MAX + pos] =
                ((unsigned long long)k << 32) | (unsigned)(gi - b * NBOX);
    }
}

// ---------------- kernel 4: bitonic sort candidates, gather top-1024 ----------------
__global__ __launch_bounds__(1024) void sort_gather(const unsigned long long* __restrict__ cand,
                                                    const unsigned* __restrict__ ncand,
                                                    const float* __restrict__ x,
                                                    const unsigned char* __restrict__ cls8,
                                                    float4* __restrict__ topbox,
                                                    float4* __restrict__ topoff,
                                                    float* __restrict__ topconf,
                                                    float* __restrict__ topcls) {
#pragma clang fp contract(off)
    __shared__ unsigned long long keys[NCAND_MAX];
    int b = blockIdx.x, t = threadIdx.x;
    int n = (int)ncand[b];
    if (n > NCAND_MAX) n = NCAND_MAX;
    for (int q = 0; q < 4; q++) {
        int s = t + q * 1024;
        keys[s] = (s < n) ? cand[(size_t)b * NCAND_MAX + s] : ~0ull;
    }
    __syncthreads();
    // ascending bitonic sort: key ascending = score descending, ties by ascending idx
    for (int k = 2; k <= NCAND_MAX; k <<= 1) {
        for (int j = k >> 1; j > 0; j >>= 1) {
            for (int q = 0; q < 4; q++) {
                int i = t + q * 1024;
                int ixj = i ^ j;
                if (ixj > i) {
                    unsigned long long a = keys[i], bb = keys[ixj];
                    bool up = ((i & k) == 0);
                    if ((a > bb) == up) { keys[i] = bb; keys[ixj] = a; }
                }
            }
            __syncthreads();
        }
    }
    // gather rank t (t in [0,1024))
    float conf; float4 box; float clsf;
    if (t < n) {
        unsigned long long key = keys[t];
        unsigned kk = (unsigned)(key >> 32);
        unsigned idx = (unsigned)(key & 0xFFFFFFFFu);
        unsigned m = ~kk;
        unsigned bits = (m & 0x80000000u) ? (m & 0x7FFFFFFFu) : ~m;
        conf = __uint_as_float(bits);           // exact original score
        size_t base = ((size_t)b * NBOX + idx) * NCH;
        float cx = x[base + 0], cy = x[base + 1], w = x[base + 2], h = x[base + 3];
        box = make_float4(cx - w * 0.5f, cy - h * 0.5f, cx + w * 0.5f, cy + h * 0.5f);
        clsf = (float)cls8[(size_t)b * NBOX + idx];
    } else {
        conf = -1.0f; box = make_float4(0.f, 0.f, 0.f, 0.f); clsf = 0.f;
    }
    int o = (b << 10) + t;
    topconf[o] = conf;
    topcls[o] = clsf;
    topbox[o] = box;
    float off = clsf * 4096.0f;
    topoff[o] = make_float4(box.x + off, box.y + off, box.z + off, box.w + off);
}

// ---------------- kernel 5: pairwise IoU suppression bitmask ----------------
// grid: BATCH*64 blocks of 256; block handles 16 i-rows x 16 j-words of one batch
__global__ __launch_bounds__(256) void iou_mask(const float4* __restrict__ topoff,
                                                unsigned long long* __restrict__ mask) {
#pragma clang fp contract(off)
    __shared__ float4 soff[KPRE];
    int b = blockIdx.x >> 6;
    int blk = blockIdx.x & 63;
    int t = threadIdx.x;
    for (int q = 0; q < 4; q++) {
        int s = t + q * 256;
        soff[s] = topoff[(b << 10) + s];
    }
    __syncthreads();
    int i = (blk << 4) + (t >> 4);
    int w = t & 15;
    float4 a = soff[i];
    float area_a = (a.z - a.x) * (a.w - a.y);
    unsigned long long bits = 0;
    int jbase = w << 6;
    for (int jj = 0; jj < 64; jj++) {
        int j = jbase + jj;
        float4 bb = soff[j];
        float area_b = (bb.z - bb.x) * (bb.w - bb.y);
        float ltx = fmaxf(a.x, bb.x), lty = fmaxf(a.y, bb.y);
        float rbx = fminf(a.z, bb.z), rby = fminf(a.w, bb.w);
        float wx = fmaxf(rbx - ltx, 0.0f), wy = fmaxf(rby - lty, 0.0f);
        float inter = wx * wy;
        float iou = inter / (area_a + area_b - inter + 1e-7f);
        if (j > i && iou > 0.45f) bits |= (1ull << jj);
    }
    mask[((size_t)((b << 10) + i) << 4) + w] = bits;
}

// ---------------- kernel 6: greedy sequential suppression (1 wave / batch) ----------------
__global__ __launch_bounds__(64) void nms_reduce(const unsigned long long* __restrict__ mask,
                                                 const float* __restrict__ topconf,
                                                 unsigned long long* __restrict__ keepbits) {
    int b = blockIdx.x, lane = threadIdx.x;
    // build keep0 bit-words via ballot; lane w (w<16) owns word w
    unsigned long long keep0w = 0;
    for (int c = 0; c < 16; c++) {
        float cf = topconf[(b << 10) + (c << 6) + lane];
        unsigned long long m = __ballot(cf > 0.0f);
        if (lane == c) keep0w = m;
    }
    const unsigned long long* mrow = mask + ((size_t)b << 14);
    bool act = lane < 16;
    unsigned long long remv = 0;
    unsigned long long p0 = act ? mrow[(size_t)0 * 16 + lane] : 0;
    unsigned long long p1 = act ? mrow[(size_t)1 * 16 + lane] : 0;
    unsigned long long p2 = act ? mrow[(size_t)2 * 16 + lane] : 0;
    unsigned long long p3 = act ? mrow[(size_t)3 * 16 + lane] : 0;
    for (int i = 0; i < 1024; i += 4) {
        unsigned long long kw, wv;
        kw = keep0w & ~remv; wv = __shfl(kw, i >> 6);
        if ((wv >> (i & 63)) & 1) remv |= p0;
        p0 = (act && i + 4 < 1024) ? mrow[(size_t)(i + 4) * 16 + lane] : 0;

        kw = keep0w & ~remv; wv = __shfl(kw, (i + 1) >> 6);
        if ((wv >> ((i + 1) & 63)) & 1) remv |= p1;
        p1 = (act && i + 5 < 1024) ? mrow[(size_t)(i + 5) * 16 + lane] : 0;

        kw = keep0w & ~remv; wv = __shfl(kw, (i + 2) >> 6);
        if ((wv >> ((i + 2) & 63)) & 1) remv |= p2;
        p2 = (act && i + 6 < 1024) ? mrow[(size_t)(i + 6) * 16 + lane] : 0;

        kw = keep0w & ~remv; wv = __shfl(kw, (i + 3) >> 6);
        if ((wv >> ((i + 3) & 63)) & 1) remv |= p3;
        p3 = (act && i + 7 < 1024) ? mrow[(size_t)(i + 7) * 16 + lane] : 0;
    }
    if (act) keepbits[b * 16 + lane] = keep0w & ~remv;
}

// ---------------- kernel 7: ordered compaction of kept entries -> dets + vmask ----------------
__global__ __launch_bounds__(1024) void finalize_kernel(const unsigned long long* __restrict__ keepbits,
                                                        const float4* __restrict__ topbox,
                                                        const float* __restrict__ topconf,
                                                        const float* __restrict__ topcls,
                                                        float* __restrict__ dets,
                                                        float* __restrict__ vmask) {
    int b = blockIdx.x, r = threadIdx.x;
    int w = r >> 6, l = r & 63;
    unsigned long long word = keepbits[b * 16 + w];
    int keep = (int)((word >> l) & 1ull);
    __shared__ int wsum[16];
    if (l == 0) wsum[w] = __popcll(word);
    __syncthreads();
    int base = 0, total = 0;
    for (int q = 0; q < 16; q++) {
        int c = wsum[q];
        total += c;
        if (q < w) base += c;
    }
    int rank = base + __popcll((l == 0) ? 0ull : (word & ((~0ull) >> (64 - l))));
    float* drow = dets + (size_t)b * (MAXDET * 6);
    float* vm = vmask + (size_t)b * MAXDET;
    if (r < MAXDET && r >= total) {
#pragma unroll
        for (int cc = 0; cc < 6; cc++) drow[r * 6 + cc] = 0.0f;
        vm[r] = 0.0f;
    }
    if (keep && rank < MAXDET) {
        int o = (b << 10) + r;
        float4 bx = topbox[o];
        drow[rank * 6 + 0] = bx.x;
        drow[rank * 6 + 1] = bx.y;
        drow[rank * 6 + 2] = bx.z;
        drow[rank * 6 + 3] = bx.w;
        drow[rank * 6 + 4] = topconf[o];
        drow[rank * 6 + 5] = topcls[o];
        vm[rank] = 1.0f;
    }
}

// ---------------- launcher ----------------
extern "C" void kernel_launch(void* const* d_in, const int* in_sizes, int n_in,
                              void* d_out, int out_size, void* d_ws, size_t ws_size,
                              hipStream_t stream) {
    const float* x = (const float*)d_in[0];
    char* w = (char*)d_ws;

    // workspace layout (bytes), total ~6.35 MB
    unsigned long long* cand     = (unsigned long long*)(w + 0);        // 16*4096*8 = 524288
    unsigned long long* mask     = (unsigned long long*)(w + 524288);   // 16*1024*16*8 = 2097152
    unsigned long long* keepbits = (unsigned long long*)(w + 2621440);  // 16*16*8 = 2048
    unsigned*           hist     = (unsigned*)(w + 2623488);            // 16*16384*4 = 1048576
    unsigned*           k32      = (unsigned*)(w + 3672064);            // 403200*4 = 1612800
    float4*             topbox   = (float4*)(w + 5284864);              // 16*1024*16 = 262144
    float4*             topoff   = (float4*)(w + 5547008);              // 262144
    float*              topconf  = (float*)(w + 5809152);               // 65536
    float*              topcls   = (float*)(w + 5874688);               // 65536
    unsigned*           cutoff   = (unsigned*)(w + 5940224);            // 64
    unsigned*           ncand    = (unsigned*)(w + 5940288);            // 64
    unsigned char*      cls8     = (unsigned char*)(w + 5940352);       // 403200
    if (ws_size < 6343552) return;  // insufficient scratch -> deterministic failure

    hipMemsetAsync(hist, 0, (size_t)BATCH * HIST_SIZE * sizeof(unsigned), stream);
    hipMemsetAsync(ncand, 0, (size_t)BATCH * sizeof(unsigned), stream);

    score_kernel<<<(BATCH * NBOX * 64) / 256, 256, 0, stream>>>(x, k32, cls8, hist);
    select_cutoff<<<BATCH, 256, 0, stream>>>(hist, cutoff);
    compact_kernel<<<(BATCH * NBOX + 255) / 256, 256, 0, stream>>>(k32, cutoff, ncand, cand);
    sort_gather<<<BATCH, 1024, 0, stream>>>(cand, ncand, x, cls8, topbox, topoff, topconf, topcls);
    iou_mask<<<BATCH * 64, 256, 0, stream>>>(topoff, mask);
    nms_reduce<<<BATCH, 64, 0, stream>>>(mask, topconf, keepbits);

    float* dets = (float*)d_out;
    float* vmask = dets + (size_t)BATCH * MAXDET * 6;
    finalize_kernel<<<BATCH, 1024, 0, stream>>>(keepbits, topbox, topconf, topcls, dets, vmask);
}

// Round 2
// 404.081 us; speedup vs baseline: 1.9755x; 1.9755x over previous
//
#include <hip/hip_runtime.h>
#include <cstdint>
#include <cstddef>

// ---------------- problem constants ----------------
#define BATCH 16
#define NBOX 25200
#define NCH 85          // 4 box + 1 obj + 80 cls
#define KPRE 1024
#define MAXDET 1000
#define NCAND_MAX 4096
#define HIST_SIZE 16384 // histogram over (key >> 18)

__device__ __forceinline__ unsigned key_of(float s) {
    // monotone map: larger score -> SMALLER key (ascending sort = descending score)
    unsigned u = __float_as_uint(s);
    unsigned m = (u & 0x80000000u) ? ~u : (u | 0x80000000u);
    return ~m;
}

// ---------------- kernel 1: per-box score/argmax, key + histogram ----------------
// 256-thread block handles 256 boxes in 2 phases of 128 rows staged in LDS.
// 2 threads per box, 40 classes each, shfl_xor combine. Valid boxes only -> hist.
__global__ __launch_bounds__(256) void score_kernel(const float* __restrict__ x,
                                                    unsigned* __restrict__ k32,
                                                    unsigned char* __restrict__ cls8,
                                                    unsigned* __restrict__ hist) {
    __shared__ float lds[128 * NCH];            // 43520 B
    int t = threadIdx.x;
    int box0 = blockIdx.x * 256;

    for (int phase = 0; phase < 2; phase++) {
        int r0 = box0 + phase * 128;
        // stage 128 rows = 10880 floats = 2720 float4 (region is 16B-aligned: r0%4==0)
        const float4* src = (const float4*)(x + (size_t)r0 * NCH);
        float4* dst = (float4*)lds;
        for (int idx = t; idx < (128 * NCH) / 4; idx += 256)
            dst[idx] = src[idx];
        __syncthreads();

        int box = t >> 1;                       // 0..127
        int half = t & 1;
        const float* row = lds + box * NCH;
        float obj = row[4];
        int cbase = 5 + half * 40;
        float v = -1e30f; int c = 0;
        #pragma unroll 8
        for (int j = 0; j < 40; j++) {
            float s = row[cbase + j] * obj;
            if (s > v) { v = s; c = half * 40 + j; }   // strict > keeps first occurrence
        }
        // combine halves; tie -> lower class index (half0)
        float ov = __shfl_xor(v, 1);
        int oc = __shfl_xor(c, 1);
        if (half == 0) { if (ov > v)  { v = ov; c = oc; } }
        else           { if (ov >= v) { v = ov; c = oc; } }

        if (half == 0) {
            int wid = r0 + box;
            bool validb = (obj > 0.25f) && (v > 0.25f);
            float score = validb ? v : -1.0f;
            unsigned k = key_of(score);
            k32[wid] = k;
            cls8[wid] = (unsigned char)c;
            if (validb) {                        // invalid boxes never join the top-k race
                int b = wid / NBOX;
                atomicAdd(&hist[b * HIST_SIZE + (k >> 18)], 1u);
            }
        }
        __syncthreads();                         // protect LDS before next phase restage
    }
}

// ---------------- kernel 2: find histogram cutoff prefix covering rank KPRE ----------------
__global__ __launch_bounds__(256) void select_cutoff(const unsigned* __restrict__ hist,
                                                     unsigned* __restrict__ cutoff) {
    int b = blockIdx.x, t = threadIdx.x;
    __shared__ unsigned part[256];
    const unsigned* h = hist + (size_t)b * HIST_SIZE;
    unsigned s = 0;
    for (int j = 0; j < HIST_SIZE / 256; j++) s += h[t * (HIST_SIZE / 256) + j];
    part[t] = s;
    __syncthreads();
    if (t == 0) {
        unsigned cum = 0;
        int chunk = 0;
        for (; chunk < 256; chunk++) {
            if (cum + part[chunk] >= KPRE) break;
            cum += part[chunk];
        }
        unsigned P = HIST_SIZE - 1;             // fewer than KPRE valid -> take all valid
        if (chunk < 256) {
            int base = chunk * (HIST_SIZE / 256);
            for (int j = 0; j < HIST_SIZE / 256; j++) {
                cum += h[base + j];
                if (cum >= KPRE) { P = base + j; break; }
            }
        }
        cutoff[b] = P;
    }
}

// ---------------- kernel 3: compact valid candidates (key64 = k32<<32 | idx) ----------------
// 2D grid: blockIdx.y = batch (wave-uniform), wave-aggregated ncand atomic.
__global__ __launch_bounds__(256) void compact_kernel(const unsigned* __restrict__ k32,
                                                      const unsigned* __restrict__ cutoff,
                                                      unsigned* __restrict__ ncand,
                                                      unsigned long long* __restrict__ cand) {
    int b = blockIdx.y;
    int i = blockIdx.x * 256 + threadIdx.x;
    bool pass = false;
    unsigned k = 0;
    if (i < NBOX) {
        k = k32[(size_t)b * NBOX + i];
        pass = ((int)k >= 0) && ((k >> 18) <= cutoff[b]);   // sign bit set = invalid (-1 score)
    }
    unsigned long long m = __ballot(pass);
    if (!m) return;
    int lane = threadIdx.x & 63;
    int rank = __popcll(lane ? (m & ((~0ull) >> (64 - lane))) : 0ull);
    int leader = (int)(__ffsll((unsigned long long)m) - 1);
    unsigned base = 0;
    if (lane == leader) base = atomicAdd(&ncand[b], (unsigned)__popcll(m));
    base = __shfl(base, leader);
    if (pass) {
        unsigned pos = base + (unsigned)rank;
        if (pos < NCAND_MAX)
            cand[(size_t)b * NCAND_MAX + pos] = ((unsigned long long)k << 32) | (unsigned)i;
    }
}

// ---------------- kernel 4: bitonic sort candidates, gather top-1024 ----------------
__global__ __launch_bounds__(1024) void sort_gather(const unsigned long long* __restrict__ cand,
                                                    const unsigned* __restrict__ ncand,
                                                    const float* __restrict__ x,
                                                    const unsigned char* __restrict__ cls8,
                                                    float4* __restrict__ topbox,
                                                    float4* __restrict__ topoff,
                                                    float* __restrict__ topconf,
                                                    float* __restrict__ topcls) {
#pragma clang fp contract(off)
    __shared__ unsigned long long keys[NCAND_MAX];
    int b = blockIdx.x, t = threadIdx.x;
    int n = (int)ncand[b];
    if (n > NCAND_MAX) n = NCAND_MAX;
    for (int q = 0; q < 4; q++) {
        int s = t + q * 1024;
        keys[s] = (s < n) ? cand[(size_t)b * NCAND_MAX + s] : ~0ull;
    }
    __syncthreads();
    // ascending bitonic sort: key ascending = score descending, ties by ascending idx
    for (int k = 2; k <= NCAND_MAX; k <<= 1) {
        for (int j = k >> 1; j > 0; j >>= 1) {
            for (int q = 0; q < 4; q++) {
                int i = t + q * 1024;
                int ixj = i ^ j;
                if (ixj > i) {
                    unsigned long long a = keys[i], bb = keys[ixj];
                    bool up = ((i & k) == 0);
                    if ((a > bb) == up) { keys[i] = bb; keys[ixj] = a; }
                }
            }
            __syncthreads();
        }
    }
    // gather rank t (t in [0,1024))
    float conf; float4 box; float clsf;
    if (t < n) {
        unsigned long long key = keys[t];
        unsigned kk = (unsigned)(key >> 32);
        unsigned idx = (unsigned)(key & 0xFFFFFFFFu);
        unsigned m = ~kk;
        unsigned bits = (m & 0x80000000u) ? (m & 0x7FFFFFFFu) : ~m;
        conf = __uint_as_float(bits);           // exact original score
        size_t base = ((size_t)b * NBOX + idx) * NCH;
        float cx = x[base + 0], cy = x[base + 1], w = x[base + 2], h = x[base + 3];
        box = make_float4(cx - w * 0.5f, cy - h * 0.5f, cx + w * 0.5f, cy + h * 0.5f);
        clsf = (float)cls8[(size_t)b * NBOX + idx];
    } else {
        conf = -1.0f; box = make_float4(0.f, 0.f, 0.f, 0.f); clsf = 0.f;
    }
    int o = (b << 10) + t;
    topconf[o] = conf;
    topcls[o] = clsf;
    topbox[o] = box;
    float off = clsf * 4096.0f;
    topoff[o] = make_float4(box.x + off, box.y + off, box.z + off, box.w + off);
}

// ---------------- kernel 5: pairwise IoU suppression bitmask ----------------
// grid: BATCH*64 blocks of 256; block handles 16 i-rows x 16 j-words of one batch
__global__ __launch_bounds__(256) void iou_mask(const float4* __restrict__ topoff,
                                                unsigned long long* __restrict__ mask) {
#pragma clang fp contract(off)
    __shared__ float4 soff[KPRE];
    int b = blockIdx.x >> 6;
    int blk = blockIdx.x & 63;
    int t = threadIdx.x;
    for (int q = 0; q < 4; q++) {
        int s = t + q * 256;
        soff[s] = topoff[(b << 10) + s];
    }
    __syncthreads();
    int i = (blk << 4) + (t >> 4);
    int w = t & 15;
    float4 a = soff[i];
    float area_a = (a.z - a.x) * (a.w - a.y);
    unsigned long long bits = 0;
    int jbase = w << 6;
    for (int jj = 0; jj < 64; jj++) {
        int j = jbase + jj;
        float4 bb = soff[j];
        float area_b = (bb.z - bb.x) * (bb.w - bb.y);
        float ltx = fmaxf(a.x, bb.x), lty = fmaxf(a.y, bb.y);
        float rbx = fminf(a.z, bb.z), rby = fminf(a.w, bb.w);
        float wx = fmaxf(rbx - ltx, 0.0f), wy = fmaxf(rby - lty, 0.0f);
        float inter = wx * wy;
        float iou = inter / (area_a + area_b - inter + 1e-7f);
        if (j > i && iou > 0.45f) bits |= (1ull << jj);
    }
    mask[((size_t)((b << 10) + i) << 4) + w] = bits;
}

// ---------------- kernel 6: greedy sequential suppression (1 wave / batch) ----------------
__global__ __launch_bounds__(64) void nms_reduce(const unsigned long long* __restrict__ mask,
                                                 const float* __restrict__ topconf,
                                                 unsigned long long* __restrict__ keepbits) {
    int b = blockIdx.x, lane = threadIdx.x;
    // build keep0 bit-words via ballot; lane w (w<16) owns word w
    unsigned long long keep0w = 0;
    for (int c = 0; c < 16; c++) {
        float cf = topconf[(b << 10) + (c << 6) + lane];
        unsigned long long m = __ballot(cf > 0.0f);
        if (lane == c) keep0w = m;
    }
    const unsigned long long* mrow = mask + ((size_t)b << 14);
    bool act = lane < 16;
    unsigned long long remv = 0;
    unsigned long long p0 = act ? mrow[(size_t)0 * 16 + lane] : 0;
    unsigned long long p1 = act ? mrow[(size_t)1 * 16 + lane] : 0;
    unsigned long long p2 = act ? mrow[(size_t)2 * 16 + lane] : 0;
    unsigned long long p3 = act ? mrow[(size_t)3 * 16 + lane] : 0;
    for (int i = 0; i < 1024; i += 4) {
        unsigned long long kw, wv;
        kw = keep0w & ~remv; wv = __shfl(kw, i >> 6);
        if ((wv >> (i & 63)) & 1) remv |= p0;
        p0 = (act && i + 4 < 1024) ? mrow[(size_t)(i + 4) * 16 + lane] : 0;

        kw = keep0w & ~remv; wv = __shfl(kw, (i + 1) >> 6);
        if ((wv >> ((i + 1) & 63)) & 1) remv |= p1;
        p1 = (act && i + 5 < 1024) ? mrow[(size_t)(i + 5) * 16 + lane] : 0;

        kw = keep0w & ~remv; wv = __shfl(kw, (i + 2) >> 6);
        if ((wv >> ((i + 2) & 63)) & 1) remv |= p2;
        p2 = (act && i + 6 < 1024) ? mrow[(size_t)(i + 6) * 16 + lane] : 0;

        kw = keep0w & ~remv; wv = __shfl(kw, (i + 3) >> 6);
        if ((wv >> ((i + 3) & 63)) & 1) remv |= p3;
        p3 = (act && i + 7 < 1024) ? mrow[(size_t)(i + 7) * 16 + lane] : 0;
    }
    if (act) keepbits[b * 16 + lane] = keep0w & ~remv;
}

// ---------------- kernel 7: ordered compaction of kept entries -> dets + vmask ----------------
__global__ __launch_bounds__(1024) void finalize_kernel(const unsigned long long* __restrict__ keepbits,
                                                        const float4* __restrict__ topbox,
                                                        const float* __restrict__ topconf,
                                                        const float* __restrict__ topcls,
                                                        float* __restrict__ dets,
                                                        float* __restrict__ vmask) {
    int b = blockIdx.x, r = threadIdx.x;
    int w = r >> 6, l = r & 63;
    unsigned long long word = keepbits[b * 16 + w];
    int keep = (int)((word >> l) & 1ull);
    __shared__ int wsum[16];
    if (l == 0) wsum[w] = __popcll(word);
    __syncthreads();
    int base = 0, total = 0;
    for (int q = 0; q < 16; q++) {
        int c = wsum[q];
        total += c;
        if (q < w) base += c;
    }
    int rank = base + __popcll((l == 0) ? 0ull : (word & ((~0ull) >> (64 - l))));
    float* drow = dets + (size_t)b * (MAXDET * 6);
    float* vm = vmask + (size_t)b * MAXDET;
    if (r < MAXDET && r >= total) {
#pragma unroll
        for (int cc = 0; cc < 6; cc++) drow[r * 6 + cc] = 0.0f;
        vm[r] = 0.0f;
    }
    if (keep && rank < MAXDET) {
        int o = (b << 10) + r;
        float4 bx = topbox[o];
        drow[rank * 6 + 0] = bx.x;
        drow[rank * 6 + 1] = bx.y;
        drow[rank * 6 + 2] = bx.z;
        drow[rank * 6 + 3] = bx.w;
        drow[rank * 6 + 4] = topconf[o];
        drow[rank * 6 + 5] = topcls[o];
        vm[rank] = 1.0f;
    }
}

// ---------------- launcher ----------------
extern "C" void kernel_launch(void* const* d_in, const int* in_sizes, int n_in,
                              void* d_out, int out_size, void* d_ws, size_t ws_size,
                              hipStream_t stream) {
    const float* x = (const float*)d_in[0];
    char* w = (char*)d_ws;

    // workspace layout (bytes), total ~6.35 MB
    unsigned long long* cand     = (unsigned long long*)(w + 0);        // 16*4096*8 = 524288
    unsigned long long* mask     = (unsigned long long*)(w + 524288);   // 16*1024*16*8 = 2097152
    unsigned long long* keepbits = (unsigned long long*)(w + 2621440);  // 16*16*8 = 2048
    unsigned*           hist     = (unsigned*)(w + 2623488);            // 16*16384*4 = 1048576
    unsigned*           k32      = (unsigned*)(w + 3672064);            // 403200*4 = 1612800
    float4*             topbox   = (float4*)(w + 5284864);              // 16*1024*16 = 262144
    float4*             topoff   = (float4*)(w + 5547008);              // 262144
    float*              topconf  = (float*)(w + 5809152);               // 65536
    float*              topcls   = (float*)(w + 5874688);               // 65536
    unsigned*           cutoff   = (unsigned*)(w + 5940224);            // 64
    unsigned*           ncand    = (unsigned*)(w + 5940288);            // 64
    unsigned char*      cls8     = (unsigned char*)(w + 5940352);       // 403200
    if (ws_size < 6343552) return;  // insufficient scratch -> deterministic failure

    hipMemsetAsync(hist, 0, (size_t)BATCH * HIST_SIZE * sizeof(unsigned), stream);
    hipMemsetAsync(ncand, 0, (size_t)BATCH * sizeof(unsigned), stream);

    score_kernel<<<(BATCH * NBOX) / 256, 256, 0, stream>>>(x, k32, cls8, hist);
    select_cutoff<<<BATCH, 256, 0, stream>>>(hist, cutoff);
    compact_kernel<<<dim3((NBOX + 255) / 256, BATCH), 256, 0, stream>>>(k32, cutoff, ncand, cand);
    sort_gather<<<BATCH, 1024, 0, stream>>>(cand, ncand, x, cls8, topbox, topoff, topconf, topcls);
    iou_mask<<<BATCH * 64, 256, 0, stream>>>(topoff, mask);
    nms_reduce<<<BATCH, 64, 0, stream>>>(mask, topconf, keepbits);

    float* dets = (float*)d_out;
    float* vmask = dets + (size_t)BATCH * MAXDET * 6;
    finalize_kernel<<<BATCH, 1024, 0, stream>>>(keepbits, topbox, topconf, topcls, dets, vmask);
}